// Round 15
// baseline (503.504 us; speedup 1.0000x reference)
//
#include <hip/hip_runtime.h>
#include <math.h>
#include <limits.h>

#define HH 1280
#define WW 1920
#define OUT_H 427
#define OUT_W 640
#define SENT 0x7fff7fff   // packed (r,c) sentinel: r=c=0x7fff

typedef short short2v __attribute__((ext_vector_type(2)));

// d^2 between packed cell a=(r<<16|c) and packed owner P=(pi<<16|pj).
// Exact int32: max real d^2 = 1279^2+1919^2 = 5.3e6; SENT d^2 ~ 1.94e9 < 2^31.
// SENT never beats a real cur and ties with SENT cur (strict <) -> reproduces
// the reference's "skip SENT cand / INT_MAX for SENT cur" bit-exactly.
__device__ __forceinline__ int dot22(int a, int P) {
#if __has_builtin(__builtin_amdgcn_sdot2)
    short2v s = __builtin_bit_cast(short2v, a) - __builtin_bit_cast(short2v, P);
    return __builtin_amdgcn_sdot2(s, s, 0, false);
#else
    int dr = (a >> 16) - (P >> 16);
    int dc = (short)a - (short)P;
    return dr * dr + dc * dc;
#endif
}
// strict-< pick with carried d^2(cur)
#define PICK(P, cur, dcur, cand)                    \
    {                                               \
        int _d = dot22((cand), (P));                \
        if (_d < (dcur)) { (cur) = (cand); (dcur) = _d; } \
    }

// ---- verified pick trees (R14), parameterized by LDS slot base ----
// G1 (dy=-k group: P1,P2,P3) at row r; slots s..s+3 = rows r, r+k, r+2k, r+3k
__device__ __forceinline__ int g1_tree(int rows[][WW], int s, int r, int j, int k) {
    bool rv1 = (r + k) < HH, rv2 = (r + 2 * k) < HH;
    bool jk = (j + k < WW);
    int Pp = (r << 16) | j;
    int cur = rows[s][j];
    int dcur = dot22(cur, Pp);
    int c1 = jk ? rows[s + 1][j + k] : SENT;
    PICK(Pp, cur, dcur, c1)
    int o1m = SENT;
    if (rv1) {
        int Pm = ((r + k) << 16) | j;
        int a = rows[s + 1][j];
        int da = dot22(a, Pm);
        int c2 = jk ? rows[s + 2][j + k] : SENT;
        PICK(Pm, a, da, c2)
        o1m = a;
    }
    PICK(Pp, cur, dcur, o1m)
    int o2q = SENT;
    int qj = j - k;
    if (rv1 && qj >= 0) {
        int Pq = ((r + k) << 16) | qj;
        int a0 = rows[s + 1][qj];
        int d0 = dot22(a0, Pq);
        PICK(Pq, a0, d0, rows[s + 2][j])
        int a1 = SENT;
        if (rv2) {
            int Pq2 = ((r + 2 * k) << 16) | qj;
            a1 = rows[s + 2][qj];
            int d1 = dot22(a1, Pq2);
            PICK(Pq2, a1, d1, rows[s + 3][j])
        }
        PICK(Pq, a0, d0, a1)
        o2q = a0;
    }
    PICK(Pp, cur, dcur, o2q)
    return cur;
}
// G2 (dy=0 group: P4,P5) at row r, row-local over g1row
__device__ __forceinline__ int g2_tree(const int* g1row, int r, int j, int k) {
    int Pp = (r << 16) | j;
    int a = g1row[j];
    int cur = a;
    int dcur = dot22(cur, Pp);
    int apk = (j + k < WW) ? g1row[j + k] : SENT;
    PICK(Pp, cur, dcur, apk)
    int o1m = SENT;
    int qj = j - k;
    if (qj >= 0) {
        int Pm = (r << 16) | qj;
        int am = g1row[qj];
        int dm = dot22(am, Pm);
        PICK(Pm, am, dm, a)
        o1m = am;
    }
    PICK(Pp, cur, dcur, o1m)
    return cur;
}
// G3 (dy=+k group: P6,P7,P8) at row p; slots s..s+3 = rows p, p-k, p-2k, p-3k
__device__ __forceinline__ int g3_tree(int rows[][WW], int s, int p, int j, int k) {
    bool rv1 = (p - k) >= 0, rv2 = (p - 2 * k) >= 0;
    bool jk = (j + k < WW);
    int Pp = (p << 16) | j;
    int cur = rows[s][j];
    int dcur = dot22(cur, Pp);
    int c1 = jk ? rows[s + 1][j + k] : SENT;
    PICK(Pp, cur, dcur, c1)
    int o1m = SENT;
    if (rv1) {
        int Pm = ((p - k) << 16) | j;
        int a = rows[s + 1][j];
        int da = dot22(a, Pm);
        int c2 = jk ? rows[s + 2][j + k] : SENT;
        PICK(Pm, a, da, c2)
        o1m = a;
    }
    PICK(Pp, cur, dcur, o1m)
    int o2q = SENT;
    int qj = j - k;
    if (rv1 && qj >= 0) {
        int Pq = ((p - k) << 16) | qj;
        int a0 = rows[s + 1][qj];
        int d0 = dot22(a0, Pq);
        PICK(Pq, a0, d0, rows[s + 2][j])
        int a1 = SENT;
        if (rv2) {
            int Pq2 = ((p - 2 * k) << 16) | qj;
            a1 = rows[s + 2][qj];
            int d1 = dot22(a1, Pq2);
            PICK(Pq2, a1, d1, rows[s + 3][j])
        }
        PICK(Pq, a0, d0, a1)
        o2q = a0;
    }
    PICK(Pp, cur, dcur, o2q)
    return cur;
}

// ---------------- scatter: project points, atomicAdd depth ----------------
// Reproduces XLA CPU dot lowering bit-exactly: plain mul/add (no FMA),
// ascending-k accumulation, translation added after.
__global__ void scatter_k(const float* __restrict__ pts,
                          const float* __restrict__ pose,
                          const float* __restrict__ extr,
                          const float* __restrict__ intr,
                          float* __restrict__ depth, int N) {
    #pragma clang fp contract(off)
    int t = blockIdx.x * blockDim.x + threadIdx.x;
    int b = blockIdx.y;
    if (t >= N) return;
    const float* p = pts + ((long)b * N + t) * 3;
    float x = p[0], y = p[1], z = p[2];
    const float* P = pose + b * 16;
    const float* E = extr + b * 16;
    const float* K = intr + b * 9;
    float wx = ((x*P[0] + y*P[1]) + z*P[2]) + P[3];
    float wy = ((x*P[4] + y*P[5]) + z*P[6]) + P[7];
    float wz = ((x*P[8] + y*P[9]) + z*P[10]) + P[11];
    float cx = ((wx*E[0] + wy*E[1]) + wz*E[2]) + E[3];
    float cy = ((wx*E[4] + wy*E[5]) + wz*E[6]) + E[7];
    float cz = ((wx*E[8] + wy*E[9]) + wz*E[10]) + E[11];
    float px = (cx*K[0] + cy*K[1]) + cz*K[2];
    float py = (cx*K[3] + cy*K[4]) + cz*K[5];
    float pz = (cx*K[6] + cy*K[7]) + cz*K[8];
    float u = px / pz, v = py / pz;
    int r = (int)floorf(v), c = (int)floorf(u);
    if (r >= 0 && r < HH && c >= 0 && c < WW) {
        float dv = sqrtf((x*x + y*y) + z*z);
        atomicAdd(depth + ((long)b * HH + r) * WW + c, dv);
    }
}

// ======== row-PAIRED LDS-staged JFA (leader i handles rows i and i+k) ========
// Leader mapping: i = (bx/k)*2k + bx%k  (even k-groups); partner ip=i+k when
// ip<HH (odd k-groups) -> every row covered exactly once.

// --- fused G1+G2, paired: stage rows i..i+4k (slots 0..4) ---
template <bool FIRST>
__global__ __launch_bounds__(512)
void jfa12p_k(const void* __restrict__ inv_, int* __restrict__ out, int k) {
    __shared__ int rows[5][WW];
    int bx = blockIdx.x, b = blockIdx.y;
    int i = (bx / k) * (2 * k) + (bx % k);
    int ip = i + k;
    bool hasP = ip < HH;
    int tid = threadIdx.x;
    if (FIRST) {
        const float* dep = (const float*)inv_ + (long)b * HH * WW;
        #pragma unroll
        for (int t = 0; t < 5; ++t) {
            int r = i + t * k;
            if (r < HH) {
                const float4* src = reinterpret_cast<const float4*>(dep + (long)r * WW);
                for (int c4 = tid; c4 < WW / 4; c4 += 512) {
                    float4 d = src[c4];
                    int4 v;
                    int c0 = c4 * 4, pb = r << 16;
                    v.x = (d.x != 0.0f) ? (pb | c0)       : SENT;
                    v.y = (d.y != 0.0f) ? (pb | (c0 + 1)) : SENT;
                    v.z = (d.z != 0.0f) ? (pb | (c0 + 2)) : SENT;
                    v.w = (d.w != 0.0f) ? (pb | (c0 + 3)) : SENT;
                    reinterpret_cast<int4*>(rows[t])[c4] = v;
                }
            } else {
                int4 sv; sv.x = sv.y = sv.z = sv.w = SENT;
                for (int c4 = tid; c4 < WW / 4; c4 += 512)
                    reinterpret_cast<int4*>(rows[t])[c4] = sv;
            }
        }
    } else {
        const int* im = (const int*)inv_ + (long)b * HH * WW;
        #pragma unroll
        for (int t = 0; t < 5; ++t) {
            int r = i + t * k;
            if (r < HH) {
                const int4* src = reinterpret_cast<const int4*>(im + (long)r * WW);
                for (int c4 = tid; c4 < WW / 4; c4 += 512)
                    reinterpret_cast<int4*>(rows[t])[c4] = src[c4];
            } else {
                int4 sv; sv.x = sv.y = sv.z = sv.w = SENT;
                for (int c4 = tid; c4 < WW / 4; c4 += 512)
                    reinterpret_cast<int4*>(rows[t])[c4] = sv;
            }
        }
    }
    __syncthreads();
    // G1 for row i (slots 0..3) and row ip (slots 1..4) -> registers
    int g1a[4], g1b[4];
    #pragma unroll
    for (int u = 0; u < 4; ++u) {
        int j = tid + u * 512;
        if (j < WW) {
            g1a[u] = g1_tree(rows, 0, i, j, k);
            if (hasP) g1b[u] = g1_tree(rows, 1, ip, j, k);
        }
    }
    __syncthreads();
    // staged slots dead now; reuse 0/1 as G1 rows
    #pragma unroll
    for (int u = 0; u < 4; ++u) {
        int j = tid + u * 512;
        if (j < WW) {
            rows[0][j] = g1a[u];
            if (hasP) rows[1][j] = g1b[u];
        }
    }
    __syncthreads();
    // G2 row-local, store both
    int* obase = out + (long)b * HH * WW;
    #pragma unroll
    for (int u = 0; u < 4; ++u) {
        int j = tid + u * 512;
        if (j < WW) {
            obase[(long)i * WW + j] = g2_tree(rows[0], i, j, k);
            if (hasP) obase[(long)ip * WW + j] = g2_tree(rows[1], ip, j, k);
        }
    }
}

// --- G3 group, paired: stage rows ip, i, i-k, i-2k, i-3k (slots 0..4) ---
__global__ __launch_bounds__(512)
void jfa3p_k(const int* __restrict__ inv_, int* __restrict__ out, int k) {
    __shared__ int rows[5][WW];
    int bx = blockIdx.x, b = blockIdx.y;
    int i = (bx / k) * (2 * k) + (bx % k);
    int ip = i + k;
    bool hasP = ip < HH;
    int tid = threadIdx.x;
    const int* im = inv_ + (long)b * HH * WW;
    #pragma unroll
    for (int t = 0; t < 5; ++t) {
        int r = ip - t * k;
        if (r >= 0 && r < HH) {
            const int4* src = reinterpret_cast<const int4*>(im + (long)r * WW);
            for (int c4 = tid; c4 < WW / 4; c4 += 512)
                reinterpret_cast<int4*>(rows[t])[c4] = src[c4];
        } else {
            int4 sv; sv.x = sv.y = sv.z = sv.w = SENT;
            for (int c4 = tid; c4 < WW / 4; c4 += 512)
                reinterpret_cast<int4*>(rows[t])[c4] = sv;
        }
    }
    __syncthreads();
    int* obase = out + (long)b * HH * WW;
    #pragma unroll
    for (int u = 0; u < 4; ++u) {
        int j = tid + u * 512;
        if (j < WW) {
            if (hasP) obase[(long)ip * WW + j] = g3_tree(rows, 0, ip, j, k);
            obase[(long)i * WW + j] = g3_tree(rows, 1, i, j, k);
        }
    }
}

// ------- fused compose + horizontal resize: one block per image row -------
__global__ __launch_bounds__(256)
void hresize_k(const float* __restrict__ depth,
               const int* __restrict__ nr,
               float* __restrict__ tmp) {
    __shared__ float fbuf[WW];
    __shared__ float dbuf[WW];
    int i = blockIdx.x, b = blockIdx.y;
    const float* dep = depth + (long)b * HH * WW;
    const float* drow = dep + (long)i * WW;
    const int* nrow = nr + ((long)b * HH + i) * WW;
    for (int j = threadIdx.x; j < WW; j += 256) {
        float dv = drow[j];
        float f, dist;
        if (dv != 0.0f) { f = dv; dist = 0.0f; }
        else {
            int nn = nrow[j];
            int rr, cc;
            if (nn == SENT) { rr = HH - 1; cc = WW - 1; }  // clip(BIG) path
            else { rr = nn >> 16; cc = nn & 0xffff; }
            f = dep[(long)rr * WW + cc];
            float drr = (float)i - (float)rr, dcc = (float)j - (float)cc;
            dist = sqrtf(drr * drr + dcc * dcc);
        }
        fbuf[j] = f; dbuf[j] = dist;
    }
    __syncthreads();
    const float inv = 3.0f;  // 1920/640
    for (int ow = threadIdx.x; ow < OUT_W; ow += 256) {
        float sf = (ow + 0.5f) * inv - 0.5f;
        int i0 = (int)ceilf(sf - inv);
        float a0 = 0.f, a1 = 0.f, wsum = 0.f;
        for (int k = 0; k < 7; ++k) {
            int iw = i0 + k;
            if (iw < 0 || iw >= WW) continue;
            float wgt = 1.0f - fabsf(sf - (float)iw) / inv;
            if (wgt <= 0.0f) continue;
            a0 += wgt * fbuf[iw]; a1 += wgt * dbuf[iw]; wsum += wgt;
        }
        long o = (((long)b * 2 + 0) * HH + i) * OUT_W + ow;
        tmp[o] = a0 / wsum;
        tmp[o + (long)HH * OUT_W] = a1 / wsum;
    }
}

// ---------------- vertical resize (H 1280->427) ----------------
__global__ void vresize_k(const float* __restrict__ tmp, float* __restrict__ out) {
    int ow = blockIdx.x * blockDim.x + threadIdx.x;
    int oh = blockIdx.y, bc = blockIdx.z;  // bc = b*2 + ch
    if (ow >= OUT_W) return;
    const float inv = (float)(1280.0 / 427.0);
    float sf = (oh + 0.5f) * inv - 0.5f;
    int i0 = (int)ceilf(sf - inv);
    float acc = 0.f, wsum = 0.f;
    const float* src = tmp + (long)bc * HH * OUT_W;
    for (int k = 0; k < 7; ++k) {
        int ih = i0 + k;
        if (ih < 0 || ih >= HH) continue;
        float wgt = 1.0f - fabsf(sf - (float)ih) / inv;
        if (wgt <= 0.0f) continue;
        acc += wgt * src[(long)ih * OUT_W + ow];
        wsum += wgt;
    }
    out[((long)bc * OUT_H + oh) * OUT_W + ow] = acc / wsum;
}

static int nleaders(int k) {
    int L = 0;
    for (int m = 0;; ++m) {
        int lo = 2 * m * k;
        if (lo >= HH) break;
        L += (HH - lo < k) ? (HH - lo) : k;
    }
    return L;
}

extern "C" void kernel_launch(void* const* d_in, const int* in_sizes, int n_in,
                              void* d_out, int out_size, void* d_ws, size_t ws_size,
                              hipStream_t stream) {
    const float* pts  = (const float*)d_in[0];
    const float* pose = (const float*)d_in[1];
    const float* extr = (const float*)d_in[2];
    const float* intr = (const float*)d_in[3];
    int B = in_sizes[1] / 16;
    int N = in_sizes[0] / (3 * B);

    char* ws = (char*)d_ws;
    size_t imgSz = (size_t)B * HH * WW;
    float* depth = (float*)ws;                  // B*H*W f32
    int*   nearA = (int*)(ws + imgSz * 4);      // B*H*W i32
    int*   nearB = (int*)(ws + imgSz * 8);      // B*H*W i32
    float* tmp   = (float*)(ws + imgSz * 12);   // B*2*H*OUT_W f32

    hipMemsetAsync(depth, 0, imgSz * sizeof(float), stream);

    dim3 bs(256);
    scatter_k<<<dim3((N + 255) / 256, B), bs, 0, stream>>>(pts, pose, extr, intr, depth, N);

    int* cur = nearA; int* nxt = nearB;
    // leading k=1 step: init fused into paired G1+G2
    {
        int L = nleaders(1);
        jfa12p_k<true><<<dim3(L, B), 512, 0, stream>>>(depth, cur, 1);
        jfa3p_k<<<dim3(L, B), 512, 0, stream>>>(cur, nxt, 1);
        int* t2 = cur; cur = nxt; nxt = t2;
    }
    const int steps_rest[11] = {1024, 512, 256, 128, 64, 32, 16, 8, 4, 2, 1};
    for (int s = 0; s < 11; ++s) {
        int k = steps_rest[s];
        int L = nleaders(k);
        jfa12p_k<false><<<dim3(L, B), 512, 0, stream>>>(cur, nxt, k);
        { int* t2 = cur; cur = nxt; nxt = t2; }
        jfa3p_k<<<dim3(L, B), 512, 0, stream>>>(cur, nxt, k);
        { int* t2 = cur; cur = nxt; nxt = t2; }
    }

    hresize_k<<<dim3(HH, B), bs, 0, stream>>>(depth, cur, tmp);
    vresize_k<<<dim3((OUT_W + 255) / 256, OUT_H, B * 2), bs, 0, stream>>>(tmp, (float*)d_out);
}